// Round 1
// baseline (898.352 us; speedup 1.0000x reference)
//
#include <hip/hip_runtime.h>

namespace {

constexpr int N   = 50000;
constexpr int E   = 600000;
constexpr int NR  = 5;
constexpr int KIN = 768;
constexpr int H   = 128;
constexpr int RD  = 200;

// ---------------- weight transpose: out[c*R + r] = in[r*C + c] ----------------
__global__ void transpose_k(const float* __restrict__ in, float* __restrict__ out, int R, int C){
  int i = blockIdx.x * 256 + threadIdx.x;
  if (i < R * C){
    int r = i / C, c = i - r * C;
    out[c * R + r] = in[i];
  }
}

// -------- relation scalars: sC[r] = (rel[r] @ Wr^T) . aC  (aC = a[256:384]) --------
__global__ void relsc_k(const float* __restrict__ rel, const float* __restrict__ Wr,
                        const float* __restrict__ a, float* __restrict__ sC){
  __shared__ float red[128];
  int n = threadIdx.x;          // 128 threads
  float aC = a[256 + n];
  for (int r = 0; r < NR; ++r){
    float p = 0.f;
    for (int k = 0; k < RD; ++k) p += rel[r * RD + k] * Wr[n * RD + k];
    red[n] = p * aC;
    __syncthreads();
    for (int s = 64; s > 0; s >>= 1){
      if (n < s) red[n] += red[n + s];
      __syncthreads();
    }
    if (n == 0) sC[r] = red[0];
    __syncthreads();
  }
}

// ---------------- tiled fp32 GEMM: out[M x 128] = A[M x K] @ Wt[K x 128] ----------------
// MODE 0: plain   MODE 1: + bias, leaky_relu(0.01)   MODE 2: elu(acc + aggM)
template<int K, int MODE>
__global__ __launch_bounds__(256) void gemm_k(const float* __restrict__ A,
    const float* __restrict__ Wt, const float* __restrict__ bias,
    const float* __restrict__ aggM, float* __restrict__ out, int M)
{
  __shared__ __align__(16) float xs[32][64];    // [kk][row]
  __shared__ __align__(16) float ws[32][128];   // [kk][col]
  const int tid  = threadIdx.x;
  const int row0 = blockIdx.x * 64;
  const int tx = tid & 15;      // col group: cols tx*4..+3 and 64+tx*4..+3
  const int ty = tid >> 4;      // row group: rows ty*4..+3
  float acc[4][8];
  #pragma unroll
  for (int r = 0; r < 4; ++r)
    #pragma unroll
    for (int c = 0; c < 8; ++c) acc[r][c] = 0.f;

  for (int k0 = 0; k0 < K; k0 += 32){
    // stage A tile (64 rows x 32 k), transposed into xs[kk][row]
    #pragma unroll
    for (int i = 0; i < 2; ++i){
      int fidx = tid * 2 + i;           // 512 float4s
      int r = fidx >> 3, c4 = fidx & 7; // 8 float4 per row
      float4 v = make_float4(0.f, 0.f, 0.f, 0.f);
      int gr = row0 + r;
      if (gr < M) v = *reinterpret_cast<const float4*>(A + (size_t)gr * K + k0 + c4 * 4);
      xs[c4*4+0][r] = v.x; xs[c4*4+1][r] = v.y; xs[c4*4+2][r] = v.z; xs[c4*4+3][r] = v.w;
    }
    // stage Wt tile (32 k x 128 cols), layout matches
    #pragma unroll
    for (int i = 0; i < 4; ++i){
      int fidx = tid + 256 * i;          // 1024 float4s
      int kk = fidx >> 5, n4 = fidx & 31;
      *reinterpret_cast<float4*>(&ws[kk][n4 * 4]) =
          *reinterpret_cast<const float4*>(Wt + (size_t)(k0 + kk) * 128 + n4 * 4);
    }
    __syncthreads();
    #pragma unroll
    for (int kk = 0; kk < 32; ++kk){
      float4 av = *reinterpret_cast<const float4*>(&xs[kk][ty * 4]);
      float4 b0 = *reinterpret_cast<const float4*>(&ws[kk][tx * 4]);
      float4 b1 = *reinterpret_cast<const float4*>(&ws[kk][64 + tx * 4]);
      float aa[4] = {av.x, av.y, av.z, av.w};
      float bb[8] = {b0.x, b0.y, b0.z, b0.w, b1.x, b1.y, b1.z, b1.w};
      #pragma unroll
      for (int r = 0; r < 4; ++r)
        #pragma unroll
        for (int c = 0; c < 8; ++c) acc[r][c] += aa[r] * bb[c];
    }
    __syncthreads();
  }

  #pragma unroll
  for (int r = 0; r < 4; ++r){
    int gr = row0 + ty * 4 + r;
    if (gr >= M) continue;
    float v[8];
    #pragma unroll
    for (int c = 0; c < 8; ++c) v[c] = acc[r][c];
    const int n0 = tx * 4, n1 = 64 + tx * 4;
    if (MODE == 1){
      #pragma unroll
      for (int c = 0; c < 4; ++c){ v[c] += bias[n0 + c]; v[4 + c] += bias[n1 + c]; }
      #pragma unroll
      for (int c = 0; c < 8; ++c) v[c] = v[c] > 0.f ? v[c] : 0.01f * v[c];
    } else if (MODE == 2){
      const float* ar = aggM + (size_t)gr * 128;
      #pragma unroll
      for (int c = 0; c < 4; ++c){ v[c] += ar[n0 + c]; v[4 + c] += ar[n1 + c]; }
      #pragma unroll
      for (int c = 0; c < 8; ++c) v[c] = v[c] > 0.f ? v[c] : __expf(v[c]) - 1.f;
    }
    float* orow = out + (size_t)gr * 128;
    *reinterpret_cast<float4*>(orow + n0) = make_float4(v[0], v[1], v[2], v[3]);
    *reinterpret_cast<float4*>(orow + n1) = make_float4(v[4], v[5], v[6], v[7]);
  }
}

// ---------------- per-node attention scalars: sA = Wx.aA, sB = Wx.aB ----------------
__global__ void nodescalar_k(const float* __restrict__ Wx, const float* __restrict__ a,
                             float* __restrict__ sA, float* __restrict__ sB, int n){
  int node = blockIdx.x * 4 + (threadIdx.x >> 6);
  int lane = threadIdx.x & 63;
  if (node >= n) return;
  const float2* row = reinterpret_cast<const float2*>(Wx + (size_t)node * 128);
  float2 v  = row[lane];
  float2 va = reinterpret_cast<const float2*>(a)[lane];
  float2 vb = reinterpret_cast<const float2*>(a + 128)[lane];
  float pa = v.x * va.x + v.y * va.y;
  float pb = v.x * vb.x + v.y * vb.y;
  #pragma unroll
  for (int off = 32; off > 0; off >>= 1){
    pa += __shfl_xor(pa, off, 64);
    pb += __shfl_xor(pb, off, 64);
  }
  if (lane == 0){ sA[node] = pa; sB[node] = pb; }
}

// ---------------- CSR build ----------------
__global__ void degcount_k(const int* __restrict__ dst, int* __restrict__ deg){
  int e = blockIdx.x * 256 + threadIdx.x;
  if (e < E) atomicAdd(&deg[dst[e]], 1);
}

__global__ void scan1_k(const int* __restrict__ deg, int* __restrict__ chunk,
                        int* __restrict__ bsums, int n){
  __shared__ int s[256];
  int tid = threadIdx.x, i = blockIdx.x * 256 + tid;
  int v = (i < n) ? deg[i] : 0;
  s[tid] = v; __syncthreads();
  for (int off = 1; off < 256; off <<= 1){
    int t = (tid >= off) ? s[tid - off] : 0;
    __syncthreads();
    s[tid] += t;
    __syncthreads();
  }
  if (i < n) chunk[i] = s[tid] - v;
  if (tid == 255) bsums[blockIdx.x] = s[255];
}

__global__ void scan2_k(const int* __restrict__ bsums, int* __restrict__ boffs, int nb){
  __shared__ int s[256];
  int tid = threadIdx.x;
  int v = (tid < nb) ? bsums[tid] : 0;
  s[tid] = v; __syncthreads();
  for (int off = 1; off < 256; off <<= 1){
    int t = (tid >= off) ? s[tid - off] : 0;
    __syncthreads();
    s[tid] += t;
    __syncthreads();
  }
  if (tid < nb) boffs[tid] = s[tid] - v;
}

__global__ void scan3_k(int* __restrict__ rowptr, const int* __restrict__ boffs,
                        int* __restrict__ cursor, int n, int total){
  int i = blockIdx.x * 256 + threadIdx.x;
  if (i < n){
    int v = rowptr[i] + boffs[blockIdx.x];
    rowptr[i] = v; cursor[i] = v;
  }
  if (i == 0) rowptr[n] = total;
}

__global__ void fill_k(const int* __restrict__ src, const int* __restrict__ dst,
                       const int* __restrict__ et, int* __restrict__ cursor,
                       int* __restrict__ csrc, int* __restrict__ ctype){
  int e = blockIdx.x * 256 + threadIdx.x;
  if (e < E){
    int d = dst[e];
    int p = atomicAdd(&cursor[d], 1);
    csrc[p]  = src[e];
    ctype[p] = et[e];
  }
}

// ------- per-node softmax + aggregate (one wave per node, no float atomics) -------
__global__ void agg_k(const float* __restrict__ Wx, const float* __restrict__ sA,
                      const float* __restrict__ sB, const float* __restrict__ sC,
                      const int* __restrict__ rowptr, const int* __restrict__ csrc,
                      const int* __restrict__ ctype, float* __restrict__ agg, int n){
  int node = blockIdx.x * 4 + (threadIdx.x >> 6);
  int lane = threadIdx.x & 63;
  if (node >= n) return;
  int p0 = rowptr[node], p1 = rowptr[node + 1];
  float sa = sA[node];
  float m = -1e30f;
  for (int p = p0; p < p1; ++p){
    float s = sa + sB[csrc[p]] + sC[ctype[p]];
    s = s > 0.f ? s : 0.2f * s;          // leaky_relu(., 0.2)
    m = fmaxf(m, s);
  }
  float a0 = 0.f, a1 = 0.f, ssum = 0.f;
  for (int p = p0; p < p1; ++p){
    int sn = csrc[p];
    float s = sa + sB[sn] + sC[ctype[p]];
    s = s > 0.f ? s : 0.2f * s;
    float ev = __expf(s - m);
    ssum += ev;
    const float* wr = Wx + (size_t)sn * 128;
    a0 += ev * wr[lane];
    a1 += ev * wr[64 + lane];
  }
  float inv = (p1 > p0) ? 1.f / ssum : 0.f;   // degree-0 guard -> agg row = 0
  float* orow = agg + (size_t)node * 128;
  orow[lane]      = a0 * inv;
  orow[64 + lane] = a1 * inv;
}

// ---------------- L2-row normalize: h /= max(||h||, 1e-12) ----------------
__global__ void norm_k(float* __restrict__ h, int n){
  int node = blockIdx.x * 4 + (threadIdx.x >> 6);
  int lane = threadIdx.x & 63;
  if (node >= n) return;
  float2* row = reinterpret_cast<float2*>(h + (size_t)node * 128);
  float2 v = row[lane];
  float ss = v.x * v.x + v.y * v.y;
  #pragma unroll
  for (int off = 32; off > 0; off >>= 1) ss += __shfl_xor(ss, off, 64);
  float nrm = sqrtf(ss);
  float sc = 1.f / fmaxf(nrm, 1e-12f);
  v.x *= sc; v.y *= sc;
  row[lane] = v;
}

} // namespace

extern "C" void kernel_launch(void* const* d_in, const int* in_sizes, int n_in,
                              void* d_out, int out_size, void* d_ws, size_t ws_size,
                              hipStream_t stream)
{
  const float* x     = (const float*)d_in[0];
  const int*   eidx  = (const int*)d_in[1];
  const int*   et    = (const int*)d_in[2];
  const float* l1W   = (const float*)d_in[3];
  const float* l1b   = (const float*)d_in[4];
  const float* l2W   = (const float*)d_in[5];
  const float* l2b   = (const float*)d_in[6];
  const float* W1    = (const float*)d_in[7];
  const float* Wr1   = (const float*)d_in[8];
  const float* a1    = (const float*)d_in[9];
  const float* Wres1 = (const float*)d_in[10];
  const float* rel1  = (const float*)d_in[11];
  const float* W2    = (const float*)d_in[12];
  const float* Wr2   = (const float*)d_in[13];
  const float* a2    = (const float*)d_in[14];
  const float* Wres2 = (const float*)d_in[15];
  const float* rel2  = (const float*)d_in[16];
  float* outp = (float*)d_out;

  const int* esrc = eidx;        // edge_index[0]
  const int* edst = eidx + E;    // edge_index[1]

  // -------- workspace layout (floats then ints), total ~84 MB --------
  float* f = (float*)d_ws;
  size_t o = 0;
  float* bufA = f + o; o += (size_t)N * H;
  float* bufB = f + o; o += (size_t)N * H;
  float* bufC = f + o; o += (size_t)N * H;
  float* Wt1  = f + o; o += (size_t)KIN * H;
  float* WtW1 = f + o; o += H * H;
  float* WtR1 = f + o; o += H * H;
  float* WtW2 = f + o; o += H * H;
  float* WtR2 = f + o; o += H * H;
  float* Wtl2 = f + o; o += H * H;
  float* sA   = f + o; o += N;
  float* sB   = f + o; o += N;
  float* sC1  = f + o; o += 8;
  float* sC2  = f + o; o += 8;
  int* wi = (int*)(f + o);
  size_t oi = 0;
  int* deg    = wi + oi; oi += N;
  int* rowptr = wi + oi; oi += N + 1;
  int* cursor = wi + oi; oi += N;
  int* bsums  = wi + oi; oi += 256;
  int* boffs  = wi + oi; oi += 256;
  int* csrc   = wi + oi; oi += E;
  int* ctype  = wi + oi; oi += E;

  const int EB    = (E + 255) / 256;   // 2344
  const int NB256 = (N + 255) / 256;   // 196
  const int GB    = (N + 63) / 64;     // 782
  const int NB4   = (N + 3) / 4;       // 12500

  // -------- CSR build (feature-independent) --------
  hipMemsetAsync(deg, 0, sizeof(int) * N, stream);
  degcount_k<<<EB, 256, 0, stream>>>(edst, deg);
  scan1_k<<<NB256, 256, 0, stream>>>(deg, rowptr, bsums, N);
  scan2_k<<<1, 256, 0, stream>>>(bsums, boffs, NB256);
  scan3_k<<<NB256, 256, 0, stream>>>(rowptr, boffs, cursor, N, E);
  fill_k<<<EB, 256, 0, stream>>>(esrc, edst, et, cursor, csrc, ctype);

  // -------- weight transposes --------
  transpose_k<<<(H * KIN + 255) / 256, 256, 0, stream>>>(l1W, Wt1, H, KIN);
  transpose_k<<<(H * H + 255) / 256, 256, 0, stream>>>(W1,    WtW1, H, H);
  transpose_k<<<(H * H + 255) / 256, 256, 0, stream>>>(Wres1, WtR1, H, H);
  transpose_k<<<(H * H + 255) / 256, 256, 0, stream>>>(W2,    WtW2, H, H);
  transpose_k<<<(H * H + 255) / 256, 256, 0, stream>>>(Wres2, WtR2, H, H);
  transpose_k<<<(H * H + 255) / 256, 256, 0, stream>>>(l2W,   Wtl2, H, H);

  relsc_k<<<1, 128, 0, stream>>>(rel1, Wr1, a1, sC1);
  relsc_k<<<1, 128, 0, stream>>>(rel2, Wr2, a2, sC2);

  // -------- layer 1: h0 = leaky(x @ l1W^T + b) --------
  gemm_k<KIN, 1><<<GB, 256, 0, stream>>>(x, Wt1, l1b, nullptr, bufA, N);

  // -------- conv 1 --------
  gemm_k<H, 0><<<GB, 256, 0, stream>>>(bufA, WtW1, nullptr, nullptr, bufB, N);   // Wx
  nodescalar_k<<<NB4, 256, 0, stream>>>(bufB, a1, sA, sB, N);
  agg_k<<<NB4, 256, 0, stream>>>(bufB, sA, sB, sC1, rowptr, csrc, ctype, bufC, N);
  gemm_k<H, 2><<<GB, 256, 0, stream>>>(bufA, WtR1, nullptr, bufC, bufC, N);      // h1 = elu(agg + h0@Wres^T)

  // -------- conv 2 --------
  gemm_k<H, 0><<<GB, 256, 0, stream>>>(bufC, WtW2, nullptr, nullptr, bufB, N);   // Wx
  nodescalar_k<<<NB4, 256, 0, stream>>>(bufB, a2, sA, sB, N);
  agg_k<<<NB4, 256, 0, stream>>>(bufB, sA, sB, sC2, rowptr, csrc, ctype, bufA, N);
  gemm_k<H, 2><<<GB, 256, 0, stream>>>(bufC, WtR2, nullptr, bufA, bufA, N);      // h2 = elu(agg + h1@Wres^T)
  norm_k<<<NB4, 256, 0, stream>>>(bufA, N);                                      // row-normalize

  // -------- layer 2: out = leaky(h2n @ l2W^T + b) --------
  gemm_k<H, 1><<<GB, 256, 0, stream>>>(bufA, Wtl2, l2b, nullptr, outp, N);
}

// Round 2
// 673.429 us; speedup vs baseline: 1.3340x; 1.3340x over previous
//
#include <hip/hip_runtime.h>

namespace {

typedef unsigned short ushort_t;
typedef unsigned int uint_t;
typedef __attribute__((ext_vector_type(8))) short bf16x8;
typedef __attribute__((ext_vector_type(4))) float f32x4;

constexpr int N   = 50000;
constexpr int E   = 600000;
constexpr int NR  = 5;
constexpr int KIN = 768;
constexpr int H   = 128;
constexpr int RD  = 200;

__device__ inline ushort_t f2b(float f){           // fp32 -> bf16 bits, RNE
  uint_t u = __builtin_bit_cast(uint_t, f);
  uint_t r = (u + 0x7FFFu + ((u >> 16) & 1u)) >> 16;
  return (ushort_t)r;
}
__device__ inline float b2f_lo(uint_t u){ return __builtin_bit_cast(float, u << 16); }
__device__ inline float b2f_hi(uint_t u){ return __builtin_bit_cast(float, u & 0xFFFF0000u); }

// ---------------- fp32 -> bf16 weight convert ----------------
__global__ void cvt_k(const float* __restrict__ in, ushort_t* __restrict__ out, int n){
  int i = blockIdx.x * 256 + threadIdx.x;
  if (i < n) out[i] = f2b(in[i]);
}

// -------- relation scalars: sC[r] = (rel[r] @ Wr^T) . aC  (fp32 exact) --------
__global__ void relsc_k(const float* __restrict__ rel, const float* __restrict__ Wr,
                        const float* __restrict__ a, float* __restrict__ sC){
  __shared__ float red[128];
  int n = threadIdx.x;          // 128 threads
  float aC = a[256 + n];
  for (int r = 0; r < NR; ++r){
    float p = 0.f;
    for (int k = 0; k < RD; ++k) p += rel[r * RD + k] * Wr[n * RD + k];
    red[n] = p * aC;
    __syncthreads();
    for (int s = 64; s > 0; s >>= 1){
      if (n < s) red[n] += red[n + s];
      __syncthreads();
    }
    if (n == 0) sC[r] = red[0];
    __syncthreads();
  }
}

// ---------------- MFMA bf16 GEMM: out[M x 128] = A[M x K] @ W^T ----------------
// W is bf16 in ORIGINAL [128 out][K in] layout == MFMA B-operand [n][k] layout.
// Block: 256 thr / 4 waves, tile 64 rows x 128 cols; wave w owns rows w*16..w*16+15.
// MODE 0: plain   MODE 1: + bias, leaky_relu(0.01)   MODE 2: elu(acc + aggM)
template<int K, int MODE, bool AFP32, bool OUTBF>
__global__ __launch_bounds__(256) void mgemm_k(const void* __restrict__ Ap,
    const ushort_t* __restrict__ Wb, const float* __restrict__ bias,
    const float* __restrict__ aggM, void* __restrict__ outp, int M)
{
  constexpr int AP = 40;  // padded LDS row strides (bf16 elems) to spread banks
  constexpr int BP = 40;
  __shared__ __align__(16) ushort_t As[64 * AP];
  __shared__ __align__(16) ushort_t Bs[128 * BP];
  const int tid  = threadIdx.x;
  const int wave = tid >> 6, lane = tid & 63;
  const int l15  = lane & 15, quad = lane >> 4;
  const int row0 = blockIdx.x * 64;

  f32x4 acc[8];
  #pragma unroll
  for (int t = 0; t < 8; ++t) acc[t] = (f32x4){0.f, 0.f, 0.f, 0.f};

  for (int k0 = 0; k0 < K; k0 += 32){
    // ---- stage A tile: 64 rows x 32 k (bf16) ----
    {
      int r = tid >> 2, q = tid & 3;           // thread -> (row, 8-elem chunk)
      int grow = row0 + r;
      ushort_t v[8] = {0,0,0,0,0,0,0,0};
      if (grow < M){
        if (AFP32){
          const float* ap = (const float*)Ap + (size_t)grow * K + k0 + q * 8;
          float4 u0 = *reinterpret_cast<const float4*>(ap);
          float4 u1 = *reinterpret_cast<const float4*>(ap + 4);
          v[0]=f2b(u0.x); v[1]=f2b(u0.y); v[2]=f2b(u0.z); v[3]=f2b(u0.w);
          v[4]=f2b(u1.x); v[5]=f2b(u1.y); v[6]=f2b(u1.z); v[7]=f2b(u1.w);
        } else {
          const uint4 u = *reinterpret_cast<const uint4*>(
              (const ushort_t*)Ap + (size_t)grow * K + k0 + q * 8);
          *reinterpret_cast<uint4*>(v) = u;
        }
      }
      *reinterpret_cast<uint4*>(&As[r * AP + q * 8]) = *reinterpret_cast<uint4*>(v);
    }
    // ---- stage B tile: 128 n-rows x 32 k (bf16), from W[n][k] ----
    {
      int n = tid >> 1, seg = tid & 1;         // each thread 32 B (two 16 B)
      const ushort_t* wp = Wb + (size_t)n * K + k0 + seg * 16;
      uint4 v0 = *reinterpret_cast<const uint4*>(wp);
      uint4 v1 = *reinterpret_cast<const uint4*>(wp + 8);
      *reinterpret_cast<uint4*>(&Bs[n * BP + seg * 16])     = v0;
      *reinterpret_cast<uint4*>(&Bs[n * BP + seg * 16 + 8]) = v1;
    }
    __syncthreads();
    // ---- MFMA: 1 A-frag + 8 B-frags -> 8 tiles of 16x16 ----
    bf16x8 af = *reinterpret_cast<const bf16x8*>(&As[(wave * 16 + l15) * AP + quad * 8]);
    #pragma unroll
    for (int t = 0; t < 8; ++t){
      bf16x8 bf = *reinterpret_cast<const bf16x8*>(&Bs[(t * 16 + l15) * BP + quad * 8]);
      acc[t] = __builtin_amdgcn_mfma_f32_16x16x32_bf16(af, bf, acc[t], 0, 0, 0);
    }
    __syncthreads();
  }

  // ---- epilogue: C/D map col=lane&15, row=quad*4+reg ----
  #pragma unroll
  for (int t = 0; t < 8; ++t){
    #pragma unroll
    for (int r = 0; r < 4; ++r){
      int grow = row0 + wave * 16 + quad * 4 + r;
      if (grow >= M) continue;
      int col = t * 16 + l15;
      float v = acc[t][r];
      if (MODE == 1){
        v += bias[col];
        v = v > 0.f ? v : 0.01f * v;
      } else if (MODE == 2){
        v += aggM[(size_t)grow * 128 + col];
        v = v > 0.f ? v : __expf(v) - 1.f;
      }
      if (OUTBF) ((ushort_t*)outp)[(size_t)grow * 128 + col] = f2b(v);
      else       ((float*)outp)   [(size_t)grow * 128 + col] = v;
    }
  }
}

// ------- per-node attention scalars from bf16 Wx: sA = Wx.aA, sB = Wx.aB -------
__global__ void nodescalar_k(const ushort_t* __restrict__ Wx, const float* __restrict__ a,
                             float* __restrict__ sA, float* __restrict__ sB, int n){
  int node = blockIdx.x * 4 + (threadIdx.x >> 6);
  int lane = threadIdx.x & 63;
  if (node >= n) return;
  uint_t u = *reinterpret_cast<const uint_t*>(Wx + (size_t)node * 128 + lane * 2);
  float c0 = b2f_lo(u), c1 = b2f_hi(u);
  float2 va = *reinterpret_cast<const float2*>(a + lane * 2);
  float2 vb = *reinterpret_cast<const float2*>(a + 128 + lane * 2);
  float pa = c0 * va.x + c1 * va.y;
  float pb = c0 * vb.x + c1 * vb.y;
  #pragma unroll
  for (int off = 32; off > 0; off >>= 1){
    pa += __shfl_xor(pa, off, 64);
    pb += __shfl_xor(pb, off, 64);
  }
  if (lane == 0){ sA[node] = pa; sB[node] = pb; }
}

// ---------------- CSR build ----------------
__global__ void degcount_k(const int* __restrict__ dst, int* __restrict__ deg){
  int e = blockIdx.x * 256 + threadIdx.x;
  if (e < E) atomicAdd(&deg[dst[e]], 1);
}

__global__ void scan1_k(const int* __restrict__ deg, int* __restrict__ chunk,
                        int* __restrict__ bsums, int n){
  __shared__ int s[256];
  int tid = threadIdx.x, i = blockIdx.x * 256 + tid;
  int v = (i < n) ? deg[i] : 0;
  s[tid] = v; __syncthreads();
  for (int off = 1; off < 256; off <<= 1){
    int t = (tid >= off) ? s[tid - off] : 0;
    __syncthreads();
    s[tid] += t;
    __syncthreads();
  }
  if (i < n) chunk[i] = s[tid] - v;
  if (tid == 255) bsums[blockIdx.x] = s[255];
}

__global__ void scan2_k(const int* __restrict__ bsums, int* __restrict__ boffs, int nb){
  __shared__ int s[256];
  int tid = threadIdx.x;
  int v = (tid < nb) ? bsums[tid] : 0;
  s[tid] = v; __syncthreads();
  for (int off = 1; off < 256; off <<= 1){
    int t = (tid >= off) ? s[tid - off] : 0;
    __syncthreads();
    s[tid] += t;
    __syncthreads();
  }
  if (tid < nb) boffs[tid] = s[tid] - v;
}

__global__ void scan3_k(int* __restrict__ rowptr, const int* __restrict__ boffs,
                        int* __restrict__ cursor, int n, int total){
  int i = blockIdx.x * 256 + threadIdx.x;
  if (i < n){
    int v = rowptr[i] + boffs[blockIdx.x];
    rowptr[i] = v; cursor[i] = v;
  }
  if (i == 0) rowptr[n] = total;
}

__global__ void fill_k(const int* __restrict__ src, const int* __restrict__ dst,
                       const int* __restrict__ et, int* __restrict__ cursor,
                       int* __restrict__ csrc, int* __restrict__ ctype){
  int e = blockIdx.x * 256 + threadIdx.x;
  if (e < E){
    int d = dst[e];
    int p = atomicAdd(&cursor[d], 1);
    csrc[p]  = src[e];
    ctype[p] = et[e];
  }
}

// ------- per-node ONLINE softmax + aggregate (one wave/node, bf16 gather) -------
__global__ void agg_k(const ushort_t* __restrict__ Wx, const float* __restrict__ sA,
                      const float* __restrict__ sB, const float* __restrict__ sC,
                      const int* __restrict__ rowptr, const int* __restrict__ csrc,
                      const int* __restrict__ ctype, float* __restrict__ agg, int n){
  int node = blockIdx.x * 4 + (threadIdx.x >> 6);
  int lane = threadIdx.x & 63;
  if (node >= n) return;
  int p0 = rowptr[node], p1 = rowptr[node + 1];
  float sa = sA[node];
  float m = -1e30f, ssum = 0.f, a0 = 0.f, a1 = 0.f;
  for (int p = p0; p < p1; ++p){
    int sn = csrc[p];
    float s = sa + sB[sn] + sC[ctype[p]];
    s = s > 0.f ? s : 0.2f * s;                   // leaky_relu(., 0.2)
    float mn   = fmaxf(m, s);
    float corr = __expf(m - mn);                  // first iter: exp(-inf)=0
    float ev   = __expf(s - mn);
    ssum = ssum * corr + ev;
    uint_t u = *reinterpret_cast<const uint_t*>(Wx + (size_t)sn * 128 + lane * 2);
    a0 = a0 * corr + ev * b2f_lo(u);
    a1 = a1 * corr + ev * b2f_hi(u);
    m = mn;
  }
  float inv = (p1 > p0) ? 1.f / ssum : 0.f;       // degree-0 guard -> zero row
  float2 w; w.x = a0 * inv; w.y = a1 * inv;
  *reinterpret_cast<float2*>(agg + (size_t)node * 128 + lane * 2) = w;
}

// ---------------- L2-row normalize bf16 h in-place ----------------
__global__ void norm_k(ushort_t* __restrict__ h, int n){
  int node = blockIdx.x * 4 + (threadIdx.x >> 6);
  int lane = threadIdx.x & 63;
  if (node >= n) return;
  uint_t* row = reinterpret_cast<uint_t*>(h + (size_t)node * 128);
  uint_t u = row[lane];
  float c0 = b2f_lo(u), c1 = b2f_hi(u);
  float ss = c0 * c0 + c1 * c1;
  #pragma unroll
  for (int off = 32; off > 0; off >>= 1) ss += __shfl_xor(ss, off, 64);
  float sc = 1.f / fmaxf(sqrtf(ss), 1e-12f);
  uint_t o = (uint_t)f2b(c0 * sc) | ((uint_t)f2b(c1 * sc) << 16);
  row[lane] = o;
}

} // namespace

extern "C" void kernel_launch(void* const* d_in, const int* in_sizes, int n_in,
                              void* d_out, int out_size, void* d_ws, size_t ws_size,
                              hipStream_t stream)
{
  const float* x     = (const float*)d_in[0];
  const int*   eidx  = (const int*)d_in[1];
  const int*   et    = (const int*)d_in[2];
  const float* l1W   = (const float*)d_in[3];
  const float* l1b   = (const float*)d_in[4];
  const float* l2W   = (const float*)d_in[5];
  const float* l2b   = (const float*)d_in[6];
  const float* W1    = (const float*)d_in[7];
  const float* Wr1   = (const float*)d_in[8];
  const float* a1    = (const float*)d_in[9];
  const float* Wres1 = (const float*)d_in[10];
  const float* rel1  = (const float*)d_in[11];
  const float* W2    = (const float*)d_in[12];
  const float* Wr2   = (const float*)d_in[13];
  const float* a2    = (const float*)d_in[14];
  const float* Wres2 = (const float*)d_in[15];
  const float* rel2  = (const float*)d_in[16];
  float* outp = (float*)d_out;

  const int* esrc = eidx;        // edge_index[0]
  const int* edst = eidx + E;    // edge_index[1]

  // -------- workspace layout --------
  float* f = (float*)d_ws;
  size_t o = 0;
  float* aggF = f + o; o += (size_t)N * H;          // fp32 aggregate (25.6 MB)
  float* sA   = f + o; o += N;
  float* sB   = f + o; o += N;
  float* sC1  = f + o; o += 8;
  float* sC2  = f + o; o += 8;
  ushort_t* us = (ushort_t*)(f + o);
  size_t ou = 0;
  ushort_t* b0   = us + ou; ou += (size_t)N * H;    // h0 bf16 (12.8 MB)
  ushort_t* b1   = us + ou; ou += (size_t)N * H;    // h1 / h2
  ushort_t* Wxb  = us + ou; ou += (size_t)N * H;    // Wx bf16
  ushort_t* l1Wb = us + ou; ou += (size_t)H * KIN;
  ushort_t* W1b  = us + ou; ou += H * H;
  ushort_t* R1b  = us + ou; ou += H * H;
  ushort_t* W2b  = us + ou; ou += H * H;
  ushort_t* R2b  = us + ou; ou += H * H;
  ushort_t* l2Wb = us + ou; ou += H * H;
  if (ou & 1) ou += 1;                               // 4B-align int region
  int* wi = (int*)(us + ou);
  size_t oi = 0;
  int* deg    = wi + oi; oi += N;
  int* rowptr = wi + oi; oi += N + 1;
  int* cursor = wi + oi; oi += N;
  int* bsums  = wi + oi; oi += 256;
  int* boffs  = wi + oi; oi += 256;
  int* csrc   = wi + oi; oi += E;
  int* ctype  = wi + oi; oi += E;

  const int EB    = (E + 255) / 256;
  const int NB256 = (N + 255) / 256;
  const int GB    = (N + 63) / 64;     // 782 blocks, 64 rows each
  const int NB4   = (N + 3) / 4;

  // -------- CSR build --------
  hipMemsetAsync(deg, 0, sizeof(int) * N, stream);
  degcount_k<<<EB, 256, 0, stream>>>(edst, deg);
  scan1_k<<<NB256, 256, 0, stream>>>(deg, rowptr, bsums, N);
  scan2_k<<<1, 256, 0, stream>>>(bsums, boffs, NB256);
  scan3_k<<<NB256, 256, 0, stream>>>(rowptr, boffs, cursor, N, E);
  fill_k<<<EB, 256, 0, stream>>>(esrc, edst, et, cursor, csrc, ctype);

  // -------- weight converts (keep original [out][in] layout == MFMA B layout) --------
  cvt_k<<<(H * KIN + 255) / 256, 256, 0, stream>>>(l1W,   l1Wb, H * KIN);
  cvt_k<<<(H * H + 255) / 256, 256, 0, stream>>>(W1,    W1b, H * H);
  cvt_k<<<(H * H + 255) / 256, 256, 0, stream>>>(Wres1, R1b, H * H);
  cvt_k<<<(H * H + 255) / 256, 256, 0, stream>>>(W2,    W2b, H * H);
  cvt_k<<<(H * H + 255) / 256, 256, 0, stream>>>(Wres2, R2b, H * H);
  cvt_k<<<(H * H + 255) / 256, 256, 0, stream>>>(l2W,   l2Wb, H * H);

  relsc_k<<<1, 128, 0, stream>>>(rel1, Wr1, a1, sC1);
  relsc_k<<<1, 128, 0, stream>>>(rel2, Wr2, a2, sC2);

  // -------- layer 1: h0 = leaky(x @ l1W^T + b)  [fp32 A -> bf16 out] --------
  mgemm_k<KIN, 1, true, true><<<GB, 256, 0, stream>>>(x, l1Wb, l1b, nullptr, b0, N);

  // -------- conv 1 --------
  mgemm_k<H, 0, false, true><<<GB, 256, 0, stream>>>(b0, W1b, nullptr, nullptr, Wxb, N);
  nodescalar_k<<<NB4, 256, 0, stream>>>(Wxb, a1, sA, sB, N);
  agg_k<<<NB4, 256, 0, stream>>>(Wxb, sA, sB, sC1, rowptr, csrc, ctype, aggF, N);
  mgemm_k<H, 2, false, true><<<GB, 256, 0, stream>>>(b0, R1b, nullptr, aggF, b1, N); // h1

  // -------- conv 2 --------
  mgemm_k<H, 0, false, true><<<GB, 256, 0, stream>>>(b1, W2b, nullptr, nullptr, Wxb, N);
  nodescalar_k<<<NB4, 256, 0, stream>>>(Wxb, a2, sA, sB, N);
  agg_k<<<NB4, 256, 0, stream>>>(Wxb, sA, sB, sC2, rowptr, csrc, ctype, aggF, N);
  mgemm_k<H, 2, false, true><<<GB, 256, 0, stream>>>(b1, R2b, nullptr, aggF, b0, N); // h2 -> b0
  norm_k<<<NB4, 256, 0, stream>>>(b0, N);

  // -------- layer 2: out = leaky(h2n @ l2W^T + b)  [fp32 out] --------
  mgemm_k<H, 1, false, false><<<GB, 256, 0, stream>>>(b0, l2Wb, l2b, nullptr, outp, N);
}

// Round 3
// 529.082 us; speedup vs baseline: 1.6979x; 1.2728x over previous
//
#include <hip/hip_runtime.h>

namespace {

typedef unsigned short ushort_t;
typedef unsigned int uint_t;
typedef __attribute__((ext_vector_type(8))) short bf16x8;
typedef __attribute__((ext_vector_type(4))) float f32x4;

constexpr int N   = 50000;
constexpr int E   = 600000;
constexpr int NR  = 5;
constexpr int KIN = 768;
constexpr int H   = 128;
constexpr int RD  = 200;

__device__ inline ushort_t f2b(float f){           // fp32 -> bf16 bits, RNE
  uint_t u = __builtin_bit_cast(uint_t, f);
  uint_t r = (u + 0x7FFFu + ((u >> 16) & 1u)) >> 16;
  return (ushort_t)r;
}
__device__ inline float b2f_lo(uint_t u){ return __builtin_bit_cast(float, u << 16); }
__device__ inline float b2f_hi(uint_t u){ return __builtin_bit_cast(float, u & 0xFFFF0000u); }

// ------------- one-shot fp32 -> bf16 convert of all 6 weight matrices -------------
// dst region is contiguous: [l1W (128x768)] [W1][Wres1][W2][Wres2][l2W] (each 128x128)
__global__ void cvt_all_k(const float* __restrict__ l1W, const float* __restrict__ W1,
                          const float* __restrict__ R1, const float* __restrict__ W2,
                          const float* __restrict__ R2, const float* __restrict__ l2W,
                          ushort_t* __restrict__ dst){
  constexpr int S0 = H * KIN;        // 98304
  constexpr int S1 = H * H;          // 16384
  int i = blockIdx.x * 256 + threadIdx.x;
  if (i >= S0 + 5 * S1) return;
  float v;
  if (i < S0) v = l1W[i];
  else {
    int j = i - S0, seg = j >> 14, off = j & (S1 - 1);
    const float* srcs[5] = {W1, R1, W2, R2, l2W};
    v = srcs[seg][off];
  }
  dst[i] = f2b(v);
}

// -------- relation scalars for both layers: sC[r] = (rel[r] @ Wr^T) . aC --------
__global__ void relsc_k(const float* __restrict__ rel1, const float* __restrict__ Wr1,
                        const float* __restrict__ a1, float* __restrict__ sC1,
                        const float* __restrict__ rel2, const float* __restrict__ Wr2,
                        const float* __restrict__ a2, float* __restrict__ sC2){
  const float* rel = blockIdx.x ? rel2 : rel1;
  const float* Wr  = blockIdx.x ? Wr2  : Wr1;
  const float* a   = blockIdx.x ? a2   : a1;
  float*       sC  = blockIdx.x ? sC2  : sC1;
  __shared__ float red[128];
  int n = threadIdx.x;          // 128 threads
  float aC = a[256 + n];
  for (int r = 0; r < NR; ++r){
    float p = 0.f;
    for (int k = 0; k < RD; ++k) p += rel[r * RD + k] * Wr[n * RD + k];
    red[n] = p * aC;
    __syncthreads();
    for (int s = 64; s > 0; s >>= 1){
      if (n < s) red[n] += red[n + s];
      __syncthreads();
    }
    if (n == 0) sC[r] = red[0];
    __syncthreads();
  }
}

// ---------------- MFMA bf16 GEMM: out[M x 128] = A[M x K] @ W^T ----------------
// W bf16 in ORIGINAL [128 out][K in] layout == MFMA B-operand [n][k] layout.
// 256 thr / 4 waves, tile 64 rows x 128 cols; wave w owns rows w*16..+15.
// MODE 0: plain bf16 out
// MODE 1: + bias, leaky_relu(0.01)
// MODE 2: elu(acc + aggM)            (+ optional fused row L2-normalize via NORM)
// MODE 3: plain bf16 out + write sA=row.aA, sB=row.aB  (avec = a vector, aA=avec, aB=avec+128)
template<int K, int MODE, bool AFP32, bool OUTBF, bool NORM>
__global__ __launch_bounds__(256) void mgemm_k(const void* __restrict__ Ap,
    const ushort_t* __restrict__ Wb, const float* __restrict__ avec,
    const float* __restrict__ aggM, void* __restrict__ outp,
    float* __restrict__ sA, float* __restrict__ sB, int M)
{
  constexpr int AP = 40;  // padded LDS row strides (bf16 elems)
  constexpr int BP = 40;
  __shared__ __align__(16) ushort_t As[64 * AP];
  __shared__ __align__(16) ushort_t Bs[128 * BP];
  const int tid  = threadIdx.x;
  const int wave = tid >> 6, lane = tid & 63;
  const int l15  = lane & 15, quad = lane >> 4;
  const int row0 = blockIdx.x * 64;

  f32x4 acc[8];
  #pragma unroll
  for (int t = 0; t < 8; ++t) acc[t] = (f32x4){0.f, 0.f, 0.f, 0.f};

  for (int k0 = 0; k0 < K; k0 += 32){
    { // ---- stage A tile: 64 rows x 32 k ----
      int r = tid >> 2, q = tid & 3;
      int grow = row0 + r;
      ushort_t v[8] = {0,0,0,0,0,0,0,0};
      if (grow < M){
        if (AFP32){
          const float* ap = (const float*)Ap + (size_t)grow * K + k0 + q * 8;
          float4 u0 = *reinterpret_cast<const float4*>(ap);
          float4 u1 = *reinterpret_cast<const float4*>(ap + 4);
          v[0]=f2b(u0.x); v[1]=f2b(u0.y); v[2]=f2b(u0.z); v[3]=f2b(u0.w);
          v[4]=f2b(u1.x); v[5]=f2b(u1.y); v[6]=f2b(u1.z); v[7]=f2b(u1.w);
        } else {
          const uint4 u = *reinterpret_cast<const uint4*>(
              (const ushort_t*)Ap + (size_t)grow * K + k0 + q * 8);
          *reinterpret_cast<uint4*>(v) = u;
        }
      }
      *reinterpret_cast<uint4*>(&As[r * AP + q * 8]) = *reinterpret_cast<uint4*>(v);
    }
    { // ---- stage B tile: 128 n-rows x 32 k from W[n][k] ----
      int n = tid >> 1, seg = tid & 1;
      const ushort_t* wp = Wb + (size_t)n * K + k0 + seg * 16;
      uint4 v0 = *reinterpret_cast<const uint4*>(wp);
      uint4 v1 = *reinterpret_cast<const uint4*>(wp + 8);
      *reinterpret_cast<uint4*>(&Bs[n * BP + seg * 16])     = v0;
      *reinterpret_cast<uint4*>(&Bs[n * BP + seg * 16 + 8]) = v1;
    }
    __syncthreads();
    bf16x8 af = *reinterpret_cast<const bf16x8*>(&As[(wave * 16 + l15) * AP + quad * 8]);
    #pragma unroll
    for (int t = 0; t < 8; ++t){
      bf16x8 bf = *reinterpret_cast<const bf16x8*>(&Bs[(t * 16 + l15) * BP + quad * 8]);
      acc[t] = __builtin_amdgcn_mfma_f32_16x16x32_bf16(af, bf, acc[t], 0, 0, 0);
    }
    __syncthreads();
  }

  // ---- epilogue: C/D map col=lane&15 -> col t*16+l15, row quad*4+r ----
  float vv[8][4];
  #pragma unroll
  for (int t = 0; t < 8; ++t){
    #pragma unroll
    for (int r = 0; r < 4; ++r){
      int grow = row0 + wave * 16 + quad * 4 + r;
      int col  = t * 16 + l15;
      float v = acc[t][r];
      if (MODE == 1){
        v += avec[col];
        v = v > 0.f ? v : 0.01f * v;
      } else if (MODE == 2){
        if (grow < M) v += aggM[(size_t)grow * 128 + col];
        v = v > 0.f ? v : __expf(v) - 1.f;
      }
      vv[t][r] = v;
    }
  }

  if (MODE == 3){
    // per-row dot with aA (avec) and aB (avec+128), reduced across the quad's 16 lanes
    #pragma unroll
    for (int r = 0; r < 4; ++r){
      float pa = 0.f, pb = 0.f;
      #pragma unroll
      for (int t = 0; t < 8; ++t){
        int col = t * 16 + l15;
        pa += vv[t][r] * avec[col];
        pb += vv[t][r] * avec[128 + col];
      }
      #pragma unroll
      for (int off = 1; off < 16; off <<= 1){
        pa += __shfl_xor(pa, off, 64);
        pb += __shfl_xor(pb, off, 64);
      }
      int grow = row0 + wave * 16 + quad * 4 + r;
      if (l15 == r && grow < M){ sA[grow] = pa; sB[grow] = pb; }
    }
  }

  if (NORM){
    // fused row L2-normalize: each row lives in one quad's vv[.][r]
    #pragma unroll
    for (int r = 0; r < 4; ++r){
      float ss = 0.f;
      #pragma unroll
      for (int t = 0; t < 8; ++t) ss += vv[t][r] * vv[t][r];
      #pragma unroll
      for (int off = 1; off < 16; off <<= 1) ss += __shfl_xor(ss, off, 64);
      float sc = 1.f / fmaxf(sqrtf(ss), 1e-12f);
      #pragma unroll
      for (int t = 0; t < 8; ++t) vv[t][r] *= sc;
    }
  }

  #pragma unroll
  for (int t = 0; t < 8; ++t){
    #pragma unroll
    for (int r = 0; r < 4; ++r){
      int grow = row0 + wave * 16 + quad * 4 + r;
      if (grow >= M) continue;
      int col = t * 16 + l15;
      if (OUTBF) ((ushort_t*)outp)[(size_t)grow * 128 + col] = f2b(vv[t][r]);
      else       ((float*)outp)   [(size_t)grow * 128 + col] = vv[t][r];
    }
  }
}

// ---------------- CSR build ----------------
__global__ void degcount_k(const int* __restrict__ dst, int* __restrict__ deg){
  int e = blockIdx.x * 256 + threadIdx.x;
  if (e < E) atomicAdd(&deg[dst[e]], 1);
}

__global__ void scan1_k(const int* __restrict__ deg, int* __restrict__ chunk,
                        int* __restrict__ bsums, int n){
  __shared__ int s[256];
  int tid = threadIdx.x, i = blockIdx.x * 256 + tid;
  int v = (i < n) ? deg[i] : 0;
  s[tid] = v; __syncthreads();
  for (int off = 1; off < 256; off <<= 1){
    int t = (tid >= off) ? s[tid - off] : 0;
    __syncthreads();
    s[tid] += t;
    __syncthreads();
  }
  if (i < n) chunk[i] = s[tid] - v;
  if (tid == 255) bsums[blockIdx.x] = s[255];
}

__global__ void scan2_k(const int* __restrict__ bsums, int* __restrict__ boffs, int nb){
  __shared__ int s[256];
  int tid = threadIdx.x;
  int v = (tid < nb) ? bsums[tid] : 0;
  s[tid] = v; __syncthreads();
  for (int off = 1; off < 256; off <<= 1){
    int t = (tid >= off) ? s[tid - off] : 0;
    __syncthreads();
    s[tid] += t;
    __syncthreads();
  }
  if (tid < nb) boffs[tid] = s[tid] - v;
}

__global__ void scan3_k(int* __restrict__ rowptr, const int* __restrict__ boffs,
                        int* __restrict__ cursor, int n, int total){
  int i = blockIdx.x * 256 + threadIdx.x;
  if (i < n){
    int v = rowptr[i] + boffs[blockIdx.x];
    rowptr[i] = v; cursor[i] = v;
  }
  if (i == 0) rowptr[n] = total;
}

__global__ void fill_k(const int* __restrict__ src, const int* __restrict__ dst,
                       const int* __restrict__ et, int* __restrict__ cursor,
                       int* __restrict__ csrc, int* __restrict__ ctype){
  int e = blockIdx.x * 256 + threadIdx.x;
  if (e < E){
    int d = dst[e];
    int p = atomicAdd(&cursor[d], 1);
    csrc[p]  = src[e];
    ctype[p] = et[e];
  }
}

// ------- per-node softmax + aggregate, latency-optimized -------
// Phase A (lane-parallel): lane e handles edge p0+e -> coalesced csrc/ctype,
//   ONE parallel sB gather, wave-reduce max & sum (shfl).
// Phase B: 4-way unrolled gather of Wx rows; index/weight via shfl broadcast.
__global__ void agg_k(const ushort_t* __restrict__ Wx, const float* __restrict__ sA,
                      const float* __restrict__ sB, const float* __restrict__ sC,
                      const int* __restrict__ rowptr, const int* __restrict__ csrc,
                      const int* __restrict__ ctype, float* __restrict__ agg, int n){
  int node = blockIdx.x * 4 + (threadIdx.x >> 6);
  int lane = threadIdx.x & 63;
  if (node >= n) return;
  int p0 = rowptr[node], p1 = rowptr[node + 1];
  int deg = p1 - p0;
  float sa = sA[node];
  float m = -1e30f, ssum = 0.f, a0 = 0.f, a1 = 0.f;

  for (int c0 = 0; c0 < deg; c0 += 64){
    int cnt = deg - c0; if (cnt > 64) cnt = 64;
    bool ok = lane < cnt;
    int p = p0 + c0 + (ok ? lane : 0);
    int sn = csrc[p];
    int tp = ctype[p];
    float s = sa + sB[sn] + sC[tp];
    s = s > 0.f ? s : 0.2f * s;                    // leaky_relu(., 0.2)
    float sv = ok ? s : -1e30f;
    #pragma unroll
    for (int off = 32; off > 0; off >>= 1) sv = fmaxf(sv, __shfl_xor(sv, off, 64));
    float mn = fmaxf(m, sv);
    float corr = __expf(m - mn);                   // first chunk: 0
    ssum *= corr; a0 *= corr; a1 *= corr;
    float ev = ok ? __expf(s - mn) : 0.f;
    float es = ev;
    #pragma unroll
    for (int off = 32; off > 0; off >>= 1) es += __shfl_xor(es, off, 64);
    ssum += es;
    int sng = ok ? sn : 0;
    m = mn;

    for (int e = 0; e < cnt; e += 4){              // e <= 60, so e+3 <= 63
      int  n0 = __shfl(sng, e,     64), n1 = __shfl(sng, e + 1, 64);
      int  n2 = __shfl(sng, e + 2, 64), n3 = __shfl(sng, e + 3, 64);
      float e0 = __shfl(ev, e,     64), e1 = __shfl(ev, e + 1, 64);
      float e2 = __shfl(ev, e + 2, 64), e3 = __shfl(ev, e + 3, 64);
      uint_t u0 = *reinterpret_cast<const uint_t*>(Wx + (size_t)n0 * 128 + lane * 2);
      uint_t u1 = *reinterpret_cast<const uint_t*>(Wx + (size_t)n1 * 128 + lane * 2);
      uint_t u2 = *reinterpret_cast<const uint_t*>(Wx + (size_t)n2 * 128 + lane * 2);
      uint_t u3 = *reinterpret_cast<const uint_t*>(Wx + (size_t)n3 * 128 + lane * 2);
      a0 += e0 * b2f_lo(u0); a1 += e0 * b2f_hi(u0);
      a0 += e1 * b2f_lo(u1); a1 += e1 * b2f_hi(u1);
      a0 += e2 * b2f_lo(u2); a1 += e2 * b2f_hi(u2);
      a0 += e3 * b2f_lo(u3); a1 += e3 * b2f_hi(u3);
    }
  }
  float inv = (deg > 0) ? 1.f / ssum : 0.f;        // degree-0 -> zero row
  float2 w; w.x = a0 * inv; w.y = a1 * inv;
  *reinterpret_cast<float2*>(agg + (size_t)node * 128 + lane * 2) = w;
}

} // namespace

extern "C" void kernel_launch(void* const* d_in, const int* in_sizes, int n_in,
                              void* d_out, int out_size, void* d_ws, size_t ws_size,
                              hipStream_t stream)
{
  const float* x     = (const float*)d_in[0];
  const int*   eidx  = (const int*)d_in[1];
  const int*   et    = (const int*)d_in[2];
  const float* l1W   = (const float*)d_in[3];
  const float* l1b   = (const float*)d_in[4];
  const float* l2W   = (const float*)d_in[5];
  const float* l2b   = (const float*)d_in[6];
  const float* W1    = (const float*)d_in[7];
  const float* Wr1   = (const float*)d_in[8];
  const float* a1    = (const float*)d_in[9];
  const float* Wres1 = (const float*)d_in[10];
  const float* rel1  = (const float*)d_in[11];
  const float* W2    = (const float*)d_in[12];
  const float* Wr2   = (const float*)d_in[13];
  const float* a2    = (const float*)d_in[14];
  const float* Wres2 = (const float*)d_in[15];
  const float* rel2  = (const float*)d_in[16];
  float* outp = (float*)d_out;

  const int* esrc = eidx;        // edge_index[0]
  const int* edst = eidx + E;    // edge_index[1]

  // -------- workspace layout --------
  float* f = (float*)d_ws;
  size_t o = 0;
  float* aggF = f + o; o += (size_t)N * H;          // fp32 aggregate
  float* sA   = f + o; o += N;
  float* sB   = f + o; o += N;
  float* sC1  = f + o; o += 8;
  float* sC2  = f + o; o += 8;
  ushort_t* us = (ushort_t*)(f + o);
  size_t ou = 0;
  ushort_t* b0   = us + ou; ou += (size_t)N * H;    // h0 / h2 bf16
  ushort_t* b1   = us + ou; ou += (size_t)N * H;    // h1
  ushort_t* Wxb  = us + ou; ou += (size_t)N * H;    // Wx bf16
  ushort_t* wtsb = us + ou; ou += (size_t)H * KIN + 5 * H * H;  // all bf16 weights, contiguous
  ushort_t* l1Wb = wtsb;
  ushort_t* W1b  = wtsb + H * KIN;
  ushort_t* R1b  = W1b + H * H;
  ushort_t* W2b  = R1b + H * H;
  ushort_t* R2b  = W2b + H * H;
  ushort_t* l2Wb = R2b + H * H;
  if (ou & 1) ou += 1;
  int* wi = (int*)(us + ou);
  size_t oi = 0;
  int* deg    = wi + oi; oi += N;
  int* rowptr = wi + oi; oi += N + 1;
  int* cursor = wi + oi; oi += N;
  int* bsums  = wi + oi; oi += 256;
  int* boffs  = wi + oi; oi += 256;
  int* csrc   = wi + oi; oi += E;
  int* ctype  = wi + oi; oi += E;

  const int EB    = (E + 255) / 256;
  const int NB256 = (N + 255) / 256;
  const int GB    = (N + 63) / 64;
  const int NB4   = (N + 3) / 4;
  const int CVB   = (H * KIN + 5 * H * H + 255) / 256;

  // -------- CSR build --------
  hipMemsetAsync(deg, 0, sizeof(int) * N, stream);
  degcount_k<<<EB, 256, 0, stream>>>(edst, deg);
  scan1_k<<<NB256, 256, 0, stream>>>(deg, rowptr, bsums, N);
  scan2_k<<<1, 256, 0, stream>>>(bsums, boffs, NB256);
  scan3_k<<<NB256, 256, 0, stream>>>(rowptr, boffs, cursor, N, E);
  fill_k<<<EB, 256, 0, stream>>>(esrc, edst, et, cursor, csrc, ctype);

  // -------- weight converts + relation scalars --------
  cvt_all_k<<<CVB, 256, 0, stream>>>(l1W, W1, Wres1, W2, Wres2, l2W, wtsb);
  relsc_k<<<2, 128, 0, stream>>>(rel1, Wr1, a1, sC1, rel2, Wr2, a2, sC2);

  // -------- layer 1: h0 = leaky(x @ l1W^T + b) --------
  mgemm_k<KIN, 1, true, true, false><<<GB, 256, 0, stream>>>(
      x, l1Wb, l1b, nullptr, b0, nullptr, nullptr, N);

  // -------- conv 1 --------
  mgemm_k<H, 3, false, true, false><<<GB, 256, 0, stream>>>(
      b0, W1b, a1, nullptr, Wxb, sA, sB, N);                     // Wx + sA/sB
  agg_k<<<NB4, 256, 0, stream>>>(Wxb, sA, sB, sC1, rowptr, csrc, ctype, aggF, N);
  mgemm_k<H, 2, false, true, false><<<GB, 256, 0, stream>>>(
      b0, R1b, nullptr, aggF, b1, nullptr, nullptr, N);          // h1

  // -------- conv 2 --------
  mgemm_k<H, 3, false, true, false><<<GB, 256, 0, stream>>>(
      b1, W2b, a2, nullptr, Wxb, sA, sB, N);                     // Wx + sA/sB
  agg_k<<<NB4, 256, 0, stream>>>(Wxb, sA, sB, sC2, rowptr, csrc, ctype, aggF, N);
  mgemm_k<H, 2, false, true, true><<<GB, 256, 0, stream>>>(
      b1, R2b, nullptr, aggF, b0, nullptr, nullptr, N);          // h2 + fused normalize

  // -------- layer 2: out = leaky(h2n @ l2W^T + b) --------
  mgemm_k<H, 1, false, false, false><<<GB, 256, 0, stream>>>(
      b0, l2Wb, l2b, nullptr, outp, nullptr, nullptr, N);
}

// Round 4
// 480.858 us; speedup vs baseline: 1.8682x; 1.1003x over previous
//
#include <hip/hip_runtime.h>

namespace {

typedef unsigned short ushort_t;
typedef unsigned int uint_t;
typedef __attribute__((ext_vector_type(8))) short bf16x8;
typedef __attribute__((ext_vector_type(4))) float f32x4;

constexpr int N   = 50000;
constexpr int E   = 600000;
constexpr int NR  = 5;
constexpr int KIN = 768;
constexpr int H   = 128;
constexpr int RD  = 200;

__device__ inline ushort_t f2b(float f){           // fp32 -> bf16 bits, RNE
  uint_t u = __builtin_bit_cast(uint_t, f);
  uint_t r = (u + 0x7FFFu + ((u >> 16) & 1u)) >> 16;
  return (ushort_t)r;
}
__device__ inline float b2f_lo(uint_t u){ return __builtin_bit_cast(float, u << 16); }
__device__ inline float b2f_hi(uint_t u){ return __builtin_bit_cast(float, u & 0xFFFF0000u); }
__device__ inline float b2f_us(ushort_t h){ return __builtin_bit_cast(float, ((uint_t)h) << 16); }

// ---- prep: weight cvt (blocks 0..703) + zero deg (704..899) + relsc (900..901) ----
__global__ void prep_k(const float* __restrict__ l1W, const float* __restrict__ W1,
                       const float* __restrict__ R1, const float* __restrict__ W2,
                       const float* __restrict__ R2, const float* __restrict__ l2W,
                       ushort_t* __restrict__ wts, int* __restrict__ deg,
                       const float* __restrict__ rel1, const float* __restrict__ Wr1,
                       const float* __restrict__ a1, float* __restrict__ sC1,
                       const float* __restrict__ rel2, const float* __restrict__ Wr2,
                       const float* __restrict__ a2, float* __restrict__ sC2){
  constexpr int S0 = H * KIN;        // 98304
  constexpr int S1 = H * H;          // 16384
  int b = blockIdx.x, tid = threadIdx.x;
  if (b < 704){                      // weight convert: 704*256 == S0 + 5*S1 exactly
    int i = b * 256 + tid;
    float v;
    if (i < S0) v = l1W[i];
    else {
      int j = i - S0, seg = j >> 14, off = j & (S1 - 1);
      const float* srcs[5] = {W1, R1, W2, R2, l2W};
      v = srcs[seg][off];
    }
    wts[i] = f2b(v);
  } else if (b < 900){               // zero deg
    int i = (b - 704) * 256 + tid;
    if (i < N) deg[i] = 0;
  } else {                           // relation scalars, one block per layer
    int L = b - 900;
    const float* rel = L ? rel2 : rel1;
    const float* Wr  = L ? Wr2  : Wr1;
    const float* a   = L ? a2   : a1;
    float*       sC  = L ? sC2  : sC1;
    __shared__ float red[256];
    int n = tid >> 1, half = tid & 1;
    float aC = a[256 + n];
    for (int r = 0; r < NR; ++r){
      float p = 0.f;
      for (int k = half * 100; k < half * 100 + 100; ++k)
        p += rel[r * RD + k] * Wr[n * RD + k];
      red[tid] = p * aC;
      __syncthreads();
      for (int s = 128; s > 0; s >>= 1){
        if (tid < s) red[tid] += red[tid + s];
        __syncthreads();
      }
      if (tid == 0) sC[r] = red[0];
      __syncthreads();
    }
  }
}

// ---------------- CSR build ----------------
__global__ void degcount_k(const int* __restrict__ dst, int* __restrict__ deg){
  int e = blockIdx.x * 256 + threadIdx.x;
  if (e < E) atomicAdd(&deg[dst[e]], 1);
}

__global__ void scan1_k(const int* __restrict__ deg, int* __restrict__ chunk,
                        int* __restrict__ bsums, int n){
  __shared__ int s[256];
  int tid = threadIdx.x, i = blockIdx.x * 256 + tid;
  int v = (i < n) ? deg[i] : 0;
  s[tid] = v; __syncthreads();
  for (int off = 1; off < 256; off <<= 1){
    int t = (tid >= off) ? s[tid - off] : 0;
    __syncthreads();
    s[tid] += t;
    __syncthreads();
  }
  if (i < n) chunk[i] = s[tid] - v;
  if (tid == 255) bsums[blockIdx.x] = s[255];
}

__global__ void scan2_k(const int* __restrict__ bsums, int* __restrict__ boffs, int nb){
  __shared__ int s[256];
  int tid = threadIdx.x;
  int v = (tid < nb) ? bsums[tid] : 0;
  s[tid] = v; __syncthreads();
  for (int off = 1; off < 256; off <<= 1){
    int t = (tid >= off) ? s[tid - off] : 0;
    __syncthreads();
    s[tid] += t;
    __syncthreads();
  }
  if (tid < nb) boffs[tid] = s[tid] - v;
}

__global__ void scan3_k(int* __restrict__ rowptr, const int* __restrict__ boffs,
                        int* __restrict__ cursor, int n, int total){
  int i = blockIdx.x * 256 + threadIdx.x;
  if (i < n){
    int v = rowptr[i] + boffs[blockIdx.x];
    rowptr[i] = v; cursor[i] = v;
  }
  if (i == 0) rowptr[n] = total;
}

// fill CSR adjacency with (type<<16)|src packed (src < 65536, type < 8)
__global__ void fill_k(const int* __restrict__ src, const int* __restrict__ dst,
                       const int* __restrict__ et, int* __restrict__ cursor,
                       int* __restrict__ cpk){
  int e = blockIdx.x * 256 + threadIdx.x;
  if (e < E){
    int d = dst[e];
    int p = atomicAdd(&cursor[d], 1);
    cpk[p] = src[e] | (et[e] << 16);
  }
}

// --------- fused double-GEMM: out1 = f1(A @ W1^T), out2 = f2(out1 @ W2^T) ---------
// W matrices bf16 in original [out][in] layout == MFMA B-operand [n][k] layout.
// 256 thr / 4 waves; tile 64 rows x 128 cols; wave w owns rows w*16..+15.
// M1: 1 = +bias1, leaky(0.01)    2 = elu(acc + agg)   [agg bf16, staged via LDS]
// NORM: fused row L2-normalize after f1
// STORE1: write bf16 tile of stage-1 result to out1
// M2: 1 = +vec2 bias, leaky(0.01), fp32 out2    3 = bf16 out2 + sA/sB (vec2 = a)
template<int K1, int M1, bool AFP32, bool NORM, bool STORE1, int M2>
__global__ __launch_bounds__(256) void gfused_k(
    const void* __restrict__ Ap, const ushort_t* __restrict__ Wb1,
    const float* __restrict__ bias1, const ushort_t* __restrict__ aggM,
    ushort_t* __restrict__ out1,
    const ushort_t* __restrict__ Wb2, const float* __restrict__ vec2,
    void* __restrict__ out2, float* __restrict__ sA, float* __restrict__ sB, int M)
{
  constexpr int AP = 40;   // k-tile staging strides (bf16 elems); 80B rows, 16B aligned
  constexpr int BP = 40;
  constexpr int CP = 136;  // stage-1 result tile stride; 272B rows, 16B aligned
  __shared__ __align__(16) ushort_t As[64 * AP];
  __shared__ __align__(16) ushort_t Bs[128 * BP];
  __shared__ __align__(16) ushort_t Cs[64 * CP];
  const int tid  = threadIdx.x;
  const int wave = tid >> 6, lane = tid & 63;
  const int l15  = lane & 15, quad = lane >> 4;
  const int row0 = blockIdx.x * 64;

  // ---- stage agg tile into Cs (coalesced); covered by first k-loop barrier ----
  if (M1 == 2){
    #pragma unroll
    for (int i = 0; i < 4; ++i){
      int idx = tid + 256 * i;               // 1024 chunks of 8 bf16
      int r = idx >> 4, c8 = idx & 15;
      int grow = row0 + r;
      uint4 v = make_uint4(0, 0, 0, 0);
      if (grow < M) v = *reinterpret_cast<const uint4*>(aggM + (size_t)grow * 128 + c8 * 8);
      *reinterpret_cast<uint4*>(&Cs[r * CP + c8 * 8]) = v;
    }
  }

  f32x4 acc[8];
  #pragma unroll
  for (int t = 0; t < 8; ++t) acc[t] = (f32x4){0.f, 0.f, 0.f, 0.f};

  // ================= GEMM 1: A[M x K1] @ W1^T =================
  for (int k0 = 0; k0 < K1; k0 += 32){
    { // stage A tile: 64 rows x 32 k
      int r = tid >> 2, q = tid & 3;
      int grow = row0 + r;
      ushort_t v[8] = {0,0,0,0,0,0,0,0};
      if (grow < M){
        if (AFP32){
          const float* ap = (const float*)Ap + (size_t)grow * K1 + k0 + q * 8;
          float4 u0 = *reinterpret_cast<const float4*>(ap);
          float4 u1 = *reinterpret_cast<const float4*>(ap + 4);
          v[0]=f2b(u0.x); v[1]=f2b(u0.y); v[2]=f2b(u0.z); v[3]=f2b(u0.w);
          v[4]=f2b(u1.x); v[5]=f2b(u1.y); v[6]=f2b(u1.z); v[7]=f2b(u1.w);
        } else {
          const uint4 u = *reinterpret_cast<const uint4*>(
              (const ushort_t*)Ap + (size_t)grow * K1 + k0 + q * 8);
          *reinterpret_cast<uint4*>(v) = u;
        }
      }
      *reinterpret_cast<uint4*>(&As[r * AP + q * 8]) = *reinterpret_cast<uint4*>(v);
    }
    { // stage B tile: 128 n-rows x 32 k from Wb1[n][k], row stride K1
      int n = tid >> 1, seg = tid & 1;
      const ushort_t* wp = Wb1 + (size_t)n * K1 + k0 + seg * 16;
      uint4 v0 = *reinterpret_cast<const uint4*>(wp);
      uint4 v1 = *reinterpret_cast<const uint4*>(wp + 8);
      *reinterpret_cast<uint4*>(&Bs[n * BP + seg * 16])     = v0;
      *reinterpret_cast<uint4*>(&Bs[n * BP + seg * 16 + 8]) = v1;
    }
    __syncthreads();
    bf16x8 af = *reinterpret_cast<const bf16x8*>(&As[(wave * 16 + l15) * AP + quad * 8]);
    #pragma unroll
    for (int t = 0; t < 8; ++t){
      bf16x8 bfr = *reinterpret_cast<const bf16x8*>(&Bs[(t * 16 + l15) * BP + quad * 8]);
      acc[t] = __builtin_amdgcn_mfma_f32_16x16x32_bf16(af, bfr, acc[t], 0, 0, 0);
    }
    __syncthreads();
  }

  // ---- epilogue 1: C/D map col=t*16+l15, local row lr=wave*16+quad*4+r ----
  float vv[8][4];
  #pragma unroll
  for (int t = 0; t < 8; ++t){
    #pragma unroll
    for (int r = 0; r < 4; ++r){
      int lr  = wave * 16 + quad * 4 + r;
      int col = t * 16 + l15;
      float v = acc[t][r];
      if (M1 == 1){
        v += bias1[col];
        v = v > 0.f ? v : 0.01f * v;
      } else { // M1 == 2
        v += b2f_us(Cs[lr * CP + col]);      // same cell this thread rewrites below
        v = v > 0.f ? v : __expf(v) - 1.f;
      }
      vv[t][r] = v;
    }
  }
  if (NORM){
    #pragma unroll
    for (int r = 0; r < 4; ++r){
      float ss = 0.f;
      #pragma unroll
      for (int t = 0; t < 8; ++t) ss += vv[t][r] * vv[t][r];
      #pragma unroll
      for (int off = 1; off < 16; off <<= 1) ss += __shfl_xor(ss, off, 64);
      float sc = 1.f / fmaxf(sqrtf(ss), 1e-12f);
      #pragma unroll
      for (int t = 0; t < 8; ++t) vv[t][r] *= sc;
    }
  }
  #pragma unroll
  for (int t = 0; t < 8; ++t){
    #pragma unroll
    for (int r = 0; r < 4; ++r){
      int lr  = wave * 16 + quad * 4 + r;
      int col = t * 16 + l15;
      int grow = row0 + lr;
      ushort_t h = f2b(vv[t][r]);
      if (STORE1 && grow < M) out1[(size_t)grow * 128 + col] = h;
      Cs[lr * CP + col] = h;
    }
  }
  __syncthreads();

  // ================= GEMM 2: Cs[64 x 128] @ W2^T =================
  #pragma unroll
  for (int t = 0; t < 8; ++t) acc[t] = (f32x4){0.f, 0.f, 0.f, 0.f};
  for (int k0 = 0; k0 < 128; k0 += 32){
    { // stage B tile from Wb2[n][k], row stride 128
      int n = tid >> 1, seg = tid & 1;
      const ushort_t* wp = Wb2 + (size_t)n * 128 + k0 + seg * 16;
      uint4 v0 = *reinterpret_cast<const uint4*>(wp);
      uint4 v1 = *reinterpret_cast<const uint4*>(wp + 8);
      *reinterpret_cast<uint4*>(&Bs[n * BP + seg * 16])     = v0;
      *reinterpret_cast<uint4*>(&Bs[n * BP + seg * 16 + 8]) = v1;
    }
    __syncthreads();
    bf16x8 af = *reinterpret_cast<const bf16x8*>(&Cs[(wave * 16 + l15) * CP + k0 + quad * 8]);
    #pragma unroll
    for (int t = 0; t < 8; ++t){
      bf16x8 bfr = *reinterpret_cast<const bf16x8*>(&Bs[(t * 16 + l15) * BP + quad * 8]);
      acc[t] = __builtin_amdgcn_mfma_f32_16x16x32_bf16(af, bfr, acc[t], 0, 0, 0);
    }
    __syncthreads();
  }

  // ---- epilogue 2 ----
  if (M2 == 1){
    #pragma unroll
    for (int t = 0; t < 8; ++t){
      #pragma unroll
      for (int r = 0; r < 4; ++r){
        int grow = row0 + wave * 16 + quad * 4 + r;
        if (grow >= M) continue;
        int col = t * 16 + l15;
        float v = acc[t][r] + vec2[col];
        v = v > 0.f ? v : 0.01f * v;
        ((float*)out2)[(size_t)grow * 128 + col] = v;
      }
    }
  } else { // M2 == 3: bf16 out + per-row sA/sB
    #pragma unroll
    for (int t = 0; t < 8; ++t){
      #pragma unroll
      for (int r = 0; r < 4; ++r){
        int grow = row0 + wave * 16 + quad * 4 + r;
        if (grow >= M) continue;
        int col = t * 16 + l15;
        ((ushort_t*)out2)[(size_t)grow * 128 + col] = f2b(acc[t][r]);
      }
    }
    #pragma unroll
    for (int r = 0; r < 4; ++r){
      float pa = 0.f, pb = 0.f;
      #pragma unroll
      for (int t = 0; t < 8; ++t){
        int col = t * 16 + l15;
        pa += acc[t][r] * vec2[col];
        pb += acc[t][r] * vec2[128 + col];
      }
      #pragma unroll
      for (int off = 1; off < 16; off <<= 1){
        pa += __shfl_xor(pa, off, 64);
        pb += __shfl_xor(pb, off, 64);
      }
      int grow = row0 + wave * 16 + quad * 4 + r;
      if (l15 == r && grow < M){ sA[grow] = pa; sB[grow] = pb; }
    }
  }
}

// ------- per-node softmax + aggregate: wave/node, packed edges, bf16 agg out -------
__global__ void agg_k(const ushort_t* __restrict__ Wx, const float* __restrict__ sA,
                      const float* __restrict__ sB, const float* __restrict__ sC,
                      const int* __restrict__ rowptr, const int* __restrict__ cpk,
                      uint_t* __restrict__ aggU, int n){
  int node = blockIdx.x * 4 + (threadIdx.x >> 6);
  int lane = threadIdx.x & 63;
  if (node >= n) return;
  int p0 = rowptr[node], p1 = rowptr[node + 1];
  int deg = p1 - p0;
  float sa = sA[node];
  float m = -1e30f, ssum = 0.f, a0 = 0.f, a1 = 0.f;

  for (int c0 = 0; c0 < deg; c0 += 64){
    int cnt = deg - c0; if (cnt > 64) cnt = 64;
    bool ok = lane < cnt;
    int p  = p0 + c0 + (ok ? lane : 0);
    int pk = cpk[p];
    int sn = pk & 0xFFFF;
    float s = sa + sB[sn] + sC[pk >> 16];
    s = s > 0.f ? s : 0.2f * s;                    // leaky_relu(., 0.2)
    float sv = ok ? s : -1e30f;
    #pragma unroll
    for (int off = 32; off > 0; off >>= 1) sv = fmaxf(sv, __shfl_xor(sv, off, 64));
    float mn = fmaxf(m, sv);
    float corr = __expf(m - mn);
    ssum *= corr; a0 *= corr; a1 *= corr;
    float ev = ok ? __expf(s - mn) : 0.f;
    float es = ev;
    #pragma unroll
    for (int off = 32; off > 0; off >>= 1) es += __shfl_xor(es, off, 64);
    ssum += es;
    int png = ok ? pk : 0;
    m = mn;

    for (int e = 0; e < cnt; e += 4){
      int  n0 = __shfl(png, e,     64) & 0xFFFF, n1 = __shfl(png, e + 1, 64) & 0xFFFF;
      int  n2 = __shfl(png, e + 2, 64) & 0xFFFF, n3 = __shfl(png, e + 3, 64) & 0xFFFF;
      float e0 = __shfl(ev, e,     64), e1 = __shfl(ev, e + 1, 64);
      float e2 = __shfl(ev, e + 2, 64), e3 = __shfl(ev, e + 3, 64);
      uint_t u0 = *reinterpret_cast<const uint_t*>(Wx + (size_t)n0 * 128 + lane * 2);
      uint_t u1 = *reinterpret_cast<const uint_t*>(Wx + (size_t)n1 * 128 + lane * 2);
      uint_t u2 = *reinterpret_cast<const uint_t*>(Wx + (size_t)n2 * 128 + lane * 2);
      uint_t u3 = *reinterpret_cast<const uint_t*>(Wx + (size_t)n3 * 128 + lane * 2);
      a0 += e0 * b2f_lo(u0); a1 += e0 * b2f_hi(u0);
      a0 += e1 * b2f_lo(u1); a1 += e1 * b2f_hi(u1);
      a0 += e2 * b2f_lo(u2); a1 += e2 * b2f_hi(u2);
      a0 += e3 * b2f_lo(u3); a1 += e3 * b2f_hi(u3);
    }
  }
  float inv = (deg > 0) ? 1.f / ssum : 0.f;        // degree-0 -> zero row
  uint_t o = (uint_t)f2b(a0 * inv) | ((uint_t)f2b(a1 * inv) << 16);
  aggU[(size_t)node * 64 + lane] = o;              // cols (2*lane, 2*lane+1)
}

} // namespace

extern "C" void kernel_launch(void* const* d_in, const int* in_sizes, int n_in,
                              void* d_out, int out_size, void* d_ws, size_t ws_size,
                              hipStream_t stream)
{
  const float* x     = (const float*)d_in[0];
  const int*   eidx  = (const int*)d_in[1];
  const int*   et    = (const int*)d_in[2];
  const float* l1W   = (const float*)d_in[3];
  const float* l1b   = (const float*)d_in[4];
  const float* l2W   = (const float*)d_in[5];
  const float* l2b   = (const float*)d_in[6];
  const float* W1    = (const float*)d_in[7];
  const float* Wr1   = (const float*)d_in[8];
  const float* a1    = (const float*)d_in[9];
  const float* Wres1 = (const float*)d_in[10];
  const float* rel1  = (const float*)d_in[11];
  const float* W2    = (const float*)d_in[12];
  const float* Wr2   = (const float*)d_in[13];
  const float* a2    = (const float*)d_in[14];
  const float* Wres2 = (const float*)d_in[15];
  const float* rel2  = (const float*)d_in[16];
  float* outp = (float*)d_out;

  const int* esrc = eidx;        // edge_index[0]
  const int* edst = eidx + E;    // edge_index[1]

  // -------- workspace layout --------
  float* f = (float*)d_ws;
  size_t o = 0;
  float* sA   = f + o; o += N;
  float* sB   = f + o; o += N;
  float* sC1  = f + o; o += 8;
  float* sC2  = f + o; o += 8;
  ushort_t* us = (ushort_t*)(f + o);
  size_t ou = 0;
  ushort_t* b0   = us + ou; ou += (size_t)N * H;    // h0 bf16
  ushort_t* b1   = us + ou; ou += (size_t)N * H;    // h1 bf16
  ushort_t* Wxb  = us + ou; ou += (size_t)N * H;    // Wx bf16
  ushort_t* aggB = us + ou; ou += (size_t)N * H;    // agg bf16
  ushort_t* wtsb = us + ou; ou += (size_t)H * KIN + 5 * H * H;
  ushort_t* l1Wb = wtsb;
  ushort_t* W1b  = wtsb + H * KIN;
  ushort_t* R1b  = W1b + H * H;
  ushort_t* W2b  = R1b + H * H;
  ushort_t* R2b  = W2b + H * H;
  ushort_t* l2Wb = R2b + H * H;
  if (ou & 1) ou += 1;
  int* wi = (int*)(us + ou);
  size_t oi = 0;
  int* deg    = wi + oi; oi += N;
  int* rowptr = wi + oi; oi += N + 1;
  int* cursor = wi + oi; oi += N;
  int* bsums  = wi + oi; oi += 256;
  int* boffs  = wi + oi; oi += 256;
  int* cpk    = wi + oi; oi += E;

  const int EB    = (E + 255) / 256;
  const int NB256 = (N + 255) / 256;
  const int GB    = (N + 63) / 64;
  const int NB4   = (N + 3) / 4;

  // -------- prep (weight cvt + deg zero + relsc) & CSR build --------
  prep_k<<<902, 256, 0, stream>>>(l1W, W1, Wres1, W2, Wres2, l2W, wtsb, deg,
                                  rel1, Wr1, a1, sC1, rel2, Wr2, a2, sC2);
  degcount_k<<<EB, 256, 0, stream>>>(edst, deg);
  scan1_k<<<NB256, 256, 0, stream>>>(deg, rowptr, bsums, N);
  scan2_k<<<1, 256, 0, stream>>>(bsums, boffs, NB256);
  scan3_k<<<NB256, 256, 0, stream>>>(rowptr, boffs, cursor, N, E);
  fill_k<<<EB, 256, 0, stream>>>(esrc, edst, et, cursor, cpk);

  // -------- G1: h0 = leaky(x@l1W^T+b) -> b0;  Wx1 = h0@W1^T -> Wxb (+sA/sB) --------
  gfused_k<KIN, 1, true, false, true, 3><<<GB, 256, 0, stream>>>(
      x, l1Wb, l1b, nullptr, b0, W1b, a1, Wxb, sA, sB, N);
  agg_k<<<NB4, 256, 0, stream>>>(Wxb, sA, sB, sC1, rowptr, cpk, (uint_t*)aggB, N);

  // -------- G2: h1 = elu(agg1 + b0@R1^T) -> b1;  Wx2 = h1@W2^T -> Wxb (+sA/sB) --------
  gfused_k<H, 2, false, false, true, 3><<<GB, 256, 0, stream>>>(
      b0, R1b, nullptr, aggB, b1, W2b, a2, Wxb, sA, sB, N);
  agg_k<<<NB4, 256, 0, stream>>>(Wxb, sA, sB, sC2, rowptr, cpk, (uint_t*)aggB, N);

  // -------- G3: h2 = normalize(elu(agg2 + b1@R2^T));  out = leaky(h2@l2W^T+b) --------
  gfused_k<H, 2, false, true, false, 1><<<GB, 256, 0, stream>>>(
      b1, R2b, nullptr, aggB, nullptr, l2Wb, l2b, outp, nullptr, nullptr, N);
}